// Round 1
// baseline (554.497 us; speedup 1.0000x reference)
//
#include <hip/hip_runtime.h>

#define BLOCK 256
#define GRID  2048
#define NGRAPH 8

// d_ws layout: float[0..7] = per-graph dots, float[8] = base (sum x^2 + t^2),
//              float[9] reinterpreted as unsigned = completed-block counter.

__global__ __launch_bounds__(BLOCK) void reduce_kernel(
    const float4* __restrict__ x4,
    const float4* __restrict__ t4,
    const int*    __restrict__ batch,
    float* __restrict__ g_acc,
    float* __restrict__ out,
    long long M /* = N*4 float4 elements */)
{
    __shared__ float s_acc[NGRAPH + 1];
    const int tid = threadIdx.x;
    if (tid < NGRAPH + 1) s_acc[tid] = 0.0f;
    __syncthreads();

    // Per-thread register accumulators: no cross-lane ops inside the hot loop.
    float acc[NGRAPH];
    #pragma unroll
    for (int i = 0; i < NGRAPH; ++i) acc[i] = 0.0f;
    float base = 0.0f;

    const long long stride = (long long)gridDim.x * (long long)blockDim.x;
    for (long long e = (long long)blockIdx.x * blockDim.x + tid; e < M; e += stride) {
        const float4 a = x4[e];
        const float4 c = t4[e];
        const int   b  = batch[e >> 2];   // 4 float4 elements per row (F=16)

        base += a.x*a.x + a.y*a.y + a.z*a.z + a.w*a.w
              + c.x*c.x + c.y*c.y + c.z*c.z + c.w*c.w;
        const float d = a.x*c.x + a.y*c.y + a.z*c.z + a.w*c.w;

        // Branchless scatter into 8 register accumulators (compile-time indices
        // after unroll -> stays in VGPRs, no scratch).
        #pragma unroll
        for (int i = 0; i < NGRAPH; ++i)
            acc[i] += (b == i) ? d : 0.0f;
    }

    // One butterfly reduction per value, once per thread (9 total).
    #pragma unroll
    for (int i = 0; i <= NGRAPH; ++i) {
        float v = (i < NGRAPH) ? acc[i] : base;
        #pragma unroll
        for (int off = 32; off > 0; off >>= 1)
            v += __shfl_xor(v, off, 64);
        if ((tid & 63) == 0)
            atomicAdd(&s_acc[i], v);
    }
    __syncthreads();

    if (tid <= NGRAPH)
        atomicAdd(&g_acc[tid], s_acc[tid]);

    // Fused finalize: last block to arrive computes the output (saves a launch).
    __threadfence();      // make this block's global atomics visible device-wide
    __syncthreads();
    if (tid == 0) {
        unsigned* cnt = (unsigned*)&g_acc[NGRAPH + 1];
        const unsigned old = atomicAdd(cnt, 1u);
        if (old == (unsigned)gridDim.x - 1u) {
            // Read accumulators via device-scope atomics (cross-XCD coherent).
            float s = 0.0f;
            #pragma unroll
            for (int i = 0; i < NGRAPH; ++i)
                s += fabsf(atomicAdd(&g_acc[i], 0.0f));
            const float b0 = atomicAdd(&g_acc[NGRAPH], 0.0f);
            out[0] = b0 - 2.0f * s;
        }
    }
}

extern "C" void kernel_launch(void* const* d_in, const int* in_sizes, int n_in,
                              void* d_out, int out_size, void* d_ws, size_t ws_size,
                              hipStream_t stream) {
    const float* inp   = (const float*)d_in[0];
    const float* tgt   = (const float*)d_in[1];
    const int*   batch = (const int*)d_in[2];
    // d_in[3] is batch_size == 8 (compile-time NGRAPH)

    const long long Nrows = (long long)in_sizes[0] / 16;  // F = 16
    const long long M     = Nrows * 4;                    // float4 elements

    float* g_acc = (float*)d_ws;
    hipMemsetAsync(g_acc, 0, (NGRAPH + 2) * sizeof(float), stream);

    reduce_kernel<<<GRID, BLOCK, 0, stream>>>(
        (const float4*)inp, (const float4*)tgt, batch, g_acc,
        (float*)d_out, M);
}

// Round 2
// 284.693 us; speedup vs baseline: 1.9477x; 1.9477x over previous
//
#include <hip/hip_runtime.h>

#define BLOCK 256
#define GRID  2048
#define NGRAPH 8

// d_ws layout: float[0..7] = per-graph dots, float[8] = base (sum x^2 + t^2)

__global__ __launch_bounds__(BLOCK) void reduce_kernel(
    const float4* __restrict__ x4,
    const float4* __restrict__ t4,
    const int*    __restrict__ batch,
    float* __restrict__ g_acc,
    long long M /* = N*4 float4 elements */)
{
    __shared__ float s_acc[NGRAPH + 1];
    const int tid = threadIdx.x;
    if (tid < NGRAPH + 1) s_acc[tid] = 0.0f;
    __syncthreads();

    float acc[NGRAPH];
    #pragma unroll
    for (int i = 0; i < NGRAPH; ++i) acc[i] = 0.0f;
    float base = 0.0f;

    const long long S     = (long long)GRID * BLOCK;   // element stride
    const long long step  = 4 * S;                     // 4-way unroll
    const long long start = (long long)blockIdx.x * BLOCK + tid;
    const long long M_pad = ((M + step - 1) / step) * step;

    const float4 z = make_float4(0.f, 0.f, 0.f, 0.f);

    for (long long e = start; e < M_pad; e += step) {
        const long long e1 = e + S, e2 = e + 2 * S, e3 = e + 3 * S;
        const bool v0 = e  < M, v1 = e1 < M, v2 = e2 < M, v3 = e3 < M;

        // ---- issue ALL loads before any consumption: 12 loads in flight ----
        float4 a0 = z, a1 = z, a2 = z, a3 = z;
        float4 c0 = z, c1 = z, c2 = z, c3 = z;
        int    b0 = 0, b1 = 0, b2 = 0, b3 = 0;
        if (v0) a0 = x4[e ];
        if (v1) a1 = x4[e1];
        if (v2) a2 = x4[e2];
        if (v3) a3 = x4[e3];
        if (v0) c0 = t4[e ];
        if (v1) c1 = t4[e1];
        if (v2) c2 = t4[e2];
        if (v3) c3 = t4[e3];
        if (v0) b0 = batch[e  >> 2];   // 4 float4 elements per row (F=16)
        if (v1) b1 = batch[e1 >> 2];
        if (v2) b2 = batch[e2 >> 2];
        if (v3) b3 = batch[e3 >> 2];

        // ---- consume ----
        #define ACCUM(a, c, b)                                                 \
            do {                                                               \
                base += a.x*a.x + a.y*a.y + a.z*a.z + a.w*a.w                  \
                      + c.x*c.x + c.y*c.y + c.z*c.z + c.w*c.w;                 \
                const float d_ = a.x*c.x + a.y*c.y + a.z*c.z + a.w*c.w;        \
                _Pragma("unroll")                                              \
                for (int i = 0; i < NGRAPH; ++i)                               \
                    acc[i] += (b == i) ? d_ : 0.0f;                            \
            } while (0)

        ACCUM(a0, c0, b0);
        ACCUM(a1, c1, b1);
        ACCUM(a2, c2, b2);
        ACCUM(a3, c3, b3);
        #undef ACCUM
    }

    // One butterfly reduction per value, once per thread (9 total).
    #pragma unroll
    for (int i = 0; i <= NGRAPH; ++i) {
        float v = (i < NGRAPH) ? acc[i] : base;
        #pragma unroll
        for (int off = 32; off > 0; off >>= 1)
            v += __shfl_xor(v, off, 64);
        if ((tid & 63) == 0)
            atomicAdd(&s_acc[i], v);
    }
    __syncthreads();

    if (tid <= NGRAPH)
        atomicAdd(&g_acc[tid], s_acc[tid]);
}

__global__ void finalize_kernel(const float* __restrict__ g_acc,
                                float* __restrict__ out)
{
    if (threadIdx.x == 0) {
        float s = 0.0f;
        #pragma unroll
        for (int i = 0; i < NGRAPH; ++i) s += fabsf(g_acc[i]);
        out[0] = g_acc[NGRAPH] - 2.0f * s;
    }
}

extern "C" void kernel_launch(void* const* d_in, const int* in_sizes, int n_in,
                              void* d_out, int out_size, void* d_ws, size_t ws_size,
                              hipStream_t stream) {
    const float* inp   = (const float*)d_in[0];
    const float* tgt   = (const float*)d_in[1];
    const int*   batch = (const int*)d_in[2];
    // d_in[3] is batch_size == 8 (compile-time NGRAPH)

    const long long Nrows = (long long)in_sizes[0] / 16;  // F = 16
    const long long M     = Nrows * 4;                    // float4 elements

    float* g_acc = (float*)d_ws;
    hipMemsetAsync(g_acc, 0, (NGRAPH + 1) * sizeof(float), stream);

    reduce_kernel<<<GRID, BLOCK, 0, stream>>>(
        (const float4*)inp, (const float4*)tgt, batch, g_acc, M);

    finalize_kernel<<<1, 64, 0, stream>>>(g_acc, (float*)d_out);
}

// Round 3
// 276.261 us; speedup vs baseline: 2.0072x; 1.0305x over previous
//
#include <hip/hip_runtime.h>

#define BLOCK 256
#define GRID  2048
#define NGRAPH 8
#define U 4
#define TILE (BLOCK * U)   // 1024 float4 elements per block-tile

// d_ws layout: float[0..7] = per-graph dots, float[8] = base (sum x^2 + t^2)

__global__ __launch_bounds__(BLOCK) void reduce_kernel(
    const float4* __restrict__ x4,
    const float4* __restrict__ t4,
    const int*    __restrict__ batch,
    float* __restrict__ g_acc,
    int M /* = N*4 float4 elements; fits in int (8e6) */)
{
    __shared__ float s_acc[NGRAPH + 1];
    const int tid = threadIdx.x;
    if (tid < NGRAPH + 1) s_acc[tid] = 0.0f;
    __syncthreads();

    float acc[NGRAPH];
    #pragma unroll
    for (int i = 0; i < NGRAPH; ++i) acc[i] = 0.0f;
    float base = 0.0f;

    const int nfull  = M / TILE;              // tiles with no bounds checks
    const int ntiles = (M + TILE - 1) / TILE; // including partial tail tile

    #define ACCUM(a, c, b)                                                 \
        do {                                                               \
            base += a.x*a.x + a.y*a.y + a.z*a.z + a.w*a.w                  \
                  + c.x*c.x + c.y*c.y + c.z*c.z + c.w*c.w;                 \
            const float d_ = a.x*c.x + a.y*c.y + a.z*c.z + a.w*c.w;        \
            _Pragma("unroll")                                              \
            for (int i = 0; i < NGRAPH; ++i)                               \
                acc[i] += (b == i) ? d_ : 0.0f;                            \
        } while (0)

    for (int t = blockIdx.x; t < ntiles; t += GRID) {
        const int e0 = t * TILE + tid;
        if (t < nfull) {
            // ---- main path: NO guards -> 12 loads issue back-to-back ----
            const float4 a0 = x4[e0            ];
            const float4 a1 = x4[e0 +     BLOCK];
            const float4 a2 = x4[e0 + 2 * BLOCK];
            const float4 a3 = x4[e0 + 3 * BLOCK];
            const float4 c0 = t4[e0            ];
            const float4 c1 = t4[e0 +     BLOCK];
            const float4 c2 = t4[e0 + 2 * BLOCK];
            const float4 c3 = t4[e0 + 3 * BLOCK];
            const int    b0 = batch[(e0            ) >> 2];
            const int    b1 = batch[(e0 +     BLOCK) >> 2];
            const int    b2 = batch[(e0 + 2 * BLOCK) >> 2];
            const int    b3 = batch[(e0 + 3 * BLOCK) >> 2];

            ACCUM(a0, c0, b0);
            ACCUM(a1, c1, b1);
            ACCUM(a2, c2, b2);
            ACCUM(a3, c3, b3);
        } else {
            // ---- tail tile (at most one per block, runs once) ----
            #pragma unroll
            for (int j = 0; j < U; ++j) {
                const int e = e0 + j * BLOCK;
                if (e < M) {
                    const float4 a = x4[e];
                    const float4 c = t4[e];
                    const int    b = batch[e >> 2];
                    ACCUM(a, c, b);
                }
            }
        }
    }
    #undef ACCUM

    // One butterfly reduction per value, once per thread (9 total).
    #pragma unroll
    for (int i = 0; i <= NGRAPH; ++i) {
        float v = (i < NGRAPH) ? acc[i] : base;
        #pragma unroll
        for (int off = 32; off > 0; off >>= 1)
            v += __shfl_xor(v, off, 64);
        if ((tid & 63) == 0)
            atomicAdd(&s_acc[i], v);
    }
    __syncthreads();

    if (tid <= NGRAPH)
        atomicAdd(&g_acc[tid], s_acc[tid]);
}

__global__ void finalize_kernel(const float* __restrict__ g_acc,
                                float* __restrict__ out)
{
    if (threadIdx.x == 0) {
        float s = 0.0f;
        #pragma unroll
        for (int i = 0; i < NGRAPH; ++i) s += fabsf(g_acc[i]);
        out[0] = g_acc[NGRAPH] - 2.0f * s;
    }
}

extern "C" void kernel_launch(void* const* d_in, const int* in_sizes, int n_in,
                              void* d_out, int out_size, void* d_ws, size_t ws_size,
                              hipStream_t stream) {
    const float* inp   = (const float*)d_in[0];
    const float* tgt   = (const float*)d_in[1];
    const int*   batch = (const int*)d_in[2];
    // d_in[3] is batch_size == 8 (compile-time NGRAPH)

    const long long Nrows = (long long)in_sizes[0] / 16;  // F = 16
    const int       M     = (int)(Nrows * 4);             // float4 elements

    float* g_acc = (float*)d_ws;
    hipMemsetAsync(g_acc, 0, (NGRAPH + 1) * sizeof(float), stream);

    reduce_kernel<<<GRID, BLOCK, 0, stream>>>(
        (const float4*)inp, (const float4*)tgt, batch, g_acc, M);

    finalize_kernel<<<1, 64, 0, stream>>>(g_acc, (float*)d_out);
}

// Round 4
// 276.019 us; speedup vs baseline: 2.0089x; 1.0009x over previous
//
#include <hip/hip_runtime.h>

#define BLOCK 256
#define GRID  2048
#define NGRAPH 8
#define U 2
#define TILE (BLOCK * U)   // 512 float4 elements per block-tile

// d_ws layout: float[0..7] = per-graph dots, float[8] = base (sum x^2 + t^2)

__global__ __launch_bounds__(BLOCK) void reduce_kernel(
    const float4* __restrict__ x4,
    const float4* __restrict__ t4,
    const int*    __restrict__ batch,
    float* __restrict__ g_acc,
    int M /* = N*4 float4 elements; fits in int */)
{
    __shared__ float s_acc[NGRAPH + 1];
    const int tid = threadIdx.x;
    if (tid < NGRAPH + 1) s_acc[tid] = 0.0f;
    __syncthreads();

    float acc[NGRAPH];
    #pragma unroll
    for (int i = 0; i < NGRAPH; ++i) acc[i] = 0.0f;
    float base = 0.0f;

    const int bx     = blockIdx.x;
    const int nfull  = M / TILE;              // tiles with no bounds checks
    const int ntiles = (M + TILE - 1) / TILE; // incl. partial tail tile
    // number of full tiles this block owns (tile indices bx, bx+GRID, ...)
    const int k = (bx < nfull) ? ((nfull - 1 - bx) / GRID + 1) : 0;

    #define ACCUM(a, c, b)                                                 \
        do {                                                               \
            base += a.x*a.x + a.y*a.y + a.z*a.z + a.w*a.w                  \
                  + c.x*c.x + c.y*c.y + c.z*c.z + c.w*c.w;                 \
            const float d_ = a.x*c.x + a.y*c.y + a.z*c.z + a.w*c.w;        \
            _Pragma("unroll")                                              \
            for (int i = 0; i < NGRAPH; ++i)                               \
                acc[i] += (b == i) ? d_ : 0.0f;                            \
        } while (0)

    // Two named register sets (A/B) -> software pipeline depth 1 with no
    // register copies; sched_barrier(0) pins the load cluster ahead of the
    // consume phase so the scheduler cannot re-serialize loads.
    float4 Aa0, Aa1, Ac0, Ac1;  int Ab0, Ab1;
    float4 Ba0, Ba1, Bc0, Bc1;  int Bb0, Bb1;

    #define LOAD_A(t)                                                      \
        do { const int e_ = (t) * TILE + tid;                              \
             Aa0 = x4[e_]; Aa1 = x4[e_ + BLOCK];                           \
             Ac0 = t4[e_]; Ac1 = t4[e_ + BLOCK];                           \
             Ab0 = batch[e_ >> 2]; Ab1 = batch[(e_ + BLOCK) >> 2]; } while (0)
    #define LOAD_B(t)                                                      \
        do { const int e_ = (t) * TILE + tid;                              \
             Ba0 = x4[e_]; Ba1 = x4[e_ + BLOCK];                           \
             Bc0 = t4[e_]; Bc1 = t4[e_ + BLOCK];                           \
             Bb0 = batch[e_ >> 2]; Bb1 = batch[(e_ + BLOCK) >> 2]; } while (0)
    #define CONS_A() do { ACCUM(Aa0, Ac0, Ab0); ACCUM(Aa1, Ac1, Ab1); } while (0)
    #define CONS_B() do { ACCUM(Ba0, Bc0, Bb0); ACCUM(Ba1, Bc1, Bb1); } while (0)

    if (k > 0) {
        LOAD_A(bx);
        int i = 1;
        for (; i + 1 < k; i += 2) {
            LOAD_B(bx + i * GRID);
            __builtin_amdgcn_sched_barrier(0);
            CONS_A();
            LOAD_A(bx + (i + 1) * GRID);
            __builtin_amdgcn_sched_barrier(0);
            CONS_B();
        }
        if (i < k) {            // odd remainder: one more tile via B
            LOAD_B(bx + i * GRID);
            __builtin_amdgcn_sched_barrier(0);
            CONS_A();
            CONS_B();
        } else {
            CONS_A();
        }
    }

    // tail partial tile (at most one in the whole grid)
    if (ntiles > nfull && (nfull % GRID) == bx) {
        const int e0 = nfull * TILE + tid;
        #pragma unroll
        for (int j = 0; j < U; ++j) {
            const int e = e0 + j * BLOCK;
            if (e < M) {
                const float4 a = x4[e];
                const float4 c = t4[e];
                const int    b = batch[e >> 2];
                ACCUM(a, c, b);
            }
        }
    }
    #undef ACCUM
    #undef LOAD_A
    #undef LOAD_B
    #undef CONS_A
    #undef CONS_B

    // One butterfly reduction per value, once per thread (9 total).
    #pragma unroll
    for (int i = 0; i <= NGRAPH; ++i) {
        float v = (i < NGRAPH) ? acc[i] : base;
        #pragma unroll
        for (int off = 32; off > 0; off >>= 1)
            v += __shfl_xor(v, off, 64);
        if ((tid & 63) == 0)
            atomicAdd(&s_acc[i], v);
    }
    __syncthreads();

    if (tid <= NGRAPH)
        atomicAdd(&g_acc[tid], s_acc[tid]);
}

__global__ void finalize_kernel(const float* __restrict__ g_acc,
                                float* __restrict__ out)
{
    if (threadIdx.x == 0) {
        float s = 0.0f;
        #pragma unroll
        for (int i = 0; i < NGRAPH; ++i) s += fabsf(g_acc[i]);
        out[0] = g_acc[NGRAPH] - 2.0f * s;
    }
}

extern "C" void kernel_launch(void* const* d_in, const int* in_sizes, int n_in,
                              void* d_out, int out_size, void* d_ws, size_t ws_size,
                              hipStream_t stream) {
    const float* inp   = (const float*)d_in[0];
    const float* tgt   = (const float*)d_in[1];
    const int*   batch = (const int*)d_in[2];
    // d_in[3] is batch_size == 8 (compile-time NGRAPH)

    const long long Nrows = (long long)in_sizes[0] / 16;  // F = 16
    const int       M     = (int)(Nrows * 4);             // float4 elements

    float* g_acc = (float*)d_ws;
    hipMemsetAsync(g_acc, 0, (NGRAPH + 1) * sizeof(float), stream);

    reduce_kernel<<<GRID, BLOCK, 0, stream>>>(
        (const float4*)inp, (const float4*)tgt, batch, g_acc, M);

    finalize_kernel<<<1, 64, 0, stream>>>(g_acc, (float*)d_out);
}